// Round 1
// baseline (12746.187 us; speedup 1.0000x reference)
//
#include <hip/hip_runtime.h>
#include <math.h>

#define N_NODES 16000
#define NGRAPH  16
#define NPG     1000      // nodes per graph
#define H       64
#define KNN     20
#define DIN     8
#define HID     32
#define NLAYERS 4
#define CD      8
#define EPS_BN  1e-5f
#define TI      16        // i-nodes per kNN block
#define IBLK    63        // ceil(1000/16)
#define INFF    __builtin_inff()

// ---------------------------------------------------------------------------
// lc_encode: x[16000,8] -> Linear(8,32)+ELU -> Linear(32,64)+ELU -> h ; also sq
// wave per node, 4 nodes/block
__global__ __launch_bounds__(256) void k_lc_encode(
    const float* __restrict__ x, const float* __restrict__ W1, const float* __restrict__ b1,
    const float* __restrict__ W2, const float* __restrict__ b2,
    float* __restrict__ h, float* __restrict__ sq)
{
    __shared__ float sW1[DIN * HID];
    __shared__ float sb1[HID];
    __shared__ float sW2[HID * H];
    __shared__ float sb2[H];
    __shared__ float sx[4][DIN];
    __shared__ float sa1[4][HID];

    int t = threadIdx.x;
    for (int ix = t; ix < DIN * HID; ix += 256) sW1[ix] = W1[ix];
    for (int ix = t; ix < HID * H;  ix += 256) sW2[ix] = W2[ix];
    if (t < HID) sb1[t] = b1[t];
    if (t < H)   sb2[t] = b2[t];

    int w = t >> 6, lane = t & 63;
    int i = blockIdx.x * 4 + w;
    if (lane < DIN) sx[w][lane] = x[i * DIN + lane];
    __syncthreads();

    // stage 1 (32 outputs; lanes 32..63 duplicate to keep flow uniform)
    int c = lane & 31;
    float a1 = sb1[c];
#pragma unroll
    for (int k = 0; k < DIN; k++) a1 += sx[w][k] * sW1[k * HID + c];
    a1 = a1 > 0.f ? a1 : expm1f(a1);
    if (lane < HID) sa1[w][lane] = a1;
    __syncthreads();

    // stage 2 (64 outputs)
    float acc = sb2[lane];
#pragma unroll
    for (int k = 0; k < HID; k++) acc += sa1[w][k] * sW2[k * H + lane];
    acc = acc > 0.f ? acc : expm1f(acc);
    h[i * H + lane] = acc;

    float s = acc * acc;
#pragma unroll
    for (int off = 32; off > 0; off >>= 1) s += __shfl_xor(s, off);
    if (lane == 0) sq[i] = s;
}

// ---------------------------------------------------------------------------
// Fused kNN: per block 16 i-nodes of one graph. d2(i,j) = sq_i + sq_j - 2*dot.
// Each wave owns 4 i's; lane covers j = lane + 64*r (r=0..15) with d2 in regs.
// Selection: 20 rounds of wave-wide butterfly argmin with lower-index tiebreak.
__global__ __launch_bounds__(256, 4) void k_knn(
    const float* __restrict__ h, const float* __restrict__ sq, int* __restrict__ knn)
{
    __shared__ float shi[TI * H];        // 16 rows x 64 (broadcast reads -> no pad)
    __shared__ float ssqi[TI];
    __shared__ float shj[64 * 64];       // 64 rows x 16 float4, xor-swizzled
    __shared__ float ssqj[64];

    int g  = blockIdx.x / IBLK;
    int ib = blockIdx.x % IBLK;
    int i0 = ib * TI;                    // graph-local
    int t = threadIdx.x, w = t >> 6, lane = t & 63;
    const float* hg  = h  + (size_t)g * NPG * H;
    const float* sqg = sq + (size_t)g * NPG;

    // stage hi tile: 16x64 floats = 256 float4, one per thread
    {
        int row = t >> 4, c4 = t & 15;
        int i = i0 + row;
        float4 v = make_float4(0.f, 0.f, 0.f, 0.f);
        if (i < NPG) v = *(const float4*)(hg + i * H + c4 * 4);
        *(float4*)(shi + row * H + c4 * 4) = v;
        if (t < TI) ssqi[t] = (i0 + t < NPG) ? sqg[i0 + t] : 0.f;
    }
    __syncthreads();

    float sqi[4];
#pragma unroll
    for (int ii = 0; ii < 4; ii++) sqi[ii] = ssqi[w * 4 + ii];

    float d2r[4][16];

#pragma unroll
    for (int r = 0; r < 16; r++) {
        if (r) __syncthreads();          // previous tile's compute done
        // stage hj tile (64 nodes x 64 floats), xor-swizzled at float4 granularity
#pragma unroll
        for (int p = 0; p < 4; p++) {
            int f = t + 256 * p;
            int row = f >> 4, c4 = f & 15;
            int jl = r * 64 + row;
            float4 v = make_float4(0.f, 0.f, 0.f, 0.f);
            if (jl < NPG) v = *(const float4*)(hg + jl * H + c4 * 4);
            *(float4*)(shj + (row * 16 + (c4 ^ (row & 15))) * 4) = v;
        }
        if (t < 64) {
            int jl = r * 64 + t;
            ssqj[t] = (jl < NPG) ? sqg[jl] : 0.f;
        }
        __syncthreads();

        float sqjv = ssqj[lane];
        float acc0 = 0.f, acc1 = 0.f, acc2 = 0.f, acc3 = 0.f;
#pragma unroll
        for (int kc = 0; kc < 16; kc++) {
            float4 bj = *(const float4*)(shj + (lane * 16 + (kc ^ (lane & 15))) * 4);
            float4 a0 = *(const float4*)(shi + (w * 4 + 0) * H + kc * 4);
            float4 a1 = *(const float4*)(shi + (w * 4 + 1) * H + kc * 4);
            float4 a2 = *(const float4*)(shi + (w * 4 + 2) * H + kc * 4);
            float4 a3 = *(const float4*)(shi + (w * 4 + 3) * H + kc * 4);
            acc0 += a0.x * bj.x + a0.y * bj.y + a0.z * bj.z + a0.w * bj.w;
            acc1 += a1.x * bj.x + a1.y * bj.y + a1.z * bj.z + a1.w * bj.w;
            acc2 += a2.x * bj.x + a2.y * bj.y + a2.z * bj.z + a2.w * bj.w;
            acc3 += a3.x * bj.x + a3.y * bj.y + a3.z * bj.z + a3.w * bj.w;
        }
        int j = r * 64 + lane;
        bool ok = (j < NPG);
        d2r[0][r] = ok ? (sqi[0] + sqjv - 2.f * acc0) : INFF;
        d2r[1][r] = ok ? (sqi[1] + sqjv - 2.f * acc1) : INFF;
        d2r[2][r] = ok ? (sqi[2] + sqjv - 2.f * acc2) : INFF;
        d2r[3][r] = ok ? (sqi[3] + sqjv - 2.f * acc3) : INFF;
    }

    // top-KNN selection, registers + shuffles only
#pragma unroll
    for (int ii = 0; ii < 4; ii++) {
        int i_loc = i0 + w * 4 + ii;
        float bv = INFF; int br = 0;
#pragma unroll
        for (int r = 0; r < 16; r++) { float v = d2r[ii][r]; if (v < bv) { bv = v; br = r; } }
        int bj = br * 64 + lane;
        int myj = 0;
#pragma unroll 1
        for (int round = 0; round < KNN; round++) {
            float v = bv; int jj = bj;
#pragma unroll
            for (int off = 1; off < 64; off <<= 1) {
                float ov = __shfl_xor(v, off);
                int   oj = __shfl_xor(jj, off);
                if (ov < v || (ov == v && oj < jj)) { v = ov; jj = oj; }
            }
            if (lane == round) myj = jj;     // lanes 0..19 collect winners in order
            if ((jj & 63) == lane) {         // owner invalidates + rescans
                int wr = jj >> 6;
                bv = INFF; br = 0;
#pragma unroll
                for (int r = 0; r < 16; r++) {
                    if (r == wr) d2r[ii][r] = INFF;
                    float vv = d2r[ii][r];
                    if (vv < bv) { bv = vv; br = r; }
                }
                bj = br * 64 + lane;
            }
        }
        if (lane < KNN && i_loc < NPG)
            knn[(size_t)(g * NPG + i_loc) * KNN + lane] = g * NPG + myj;
    }
}

// ---------------------------------------------------------------------------
// T = h @ (W1 - W2) + b ; U = h @ W2.   W: [128][64] (rows 0..63 = x_i part).
// 16 nodes/block; lane = (node%4)*16... mapping: wave w covers nodes w*4..w*4+3,
// lane = nl*16 + cg, each thread does 4 channels (float4).
__global__ __launch_bounds__(256) void k_tu(
    const float* __restrict__ h, const float* __restrict__ W, const float* __restrict__ b,
    float* __restrict__ T, float* __restrict__ U)
{
    __shared__ float sWd[H * H];
    __shared__ float sW2[H * H];
    __shared__ float sh[16 * H];
    __shared__ float sb[H];
    int t = threadIdx.x;
    for (int ix = t; ix < H * H; ix += 256) {
        float w1 = W[ix], w2 = W[H * H + ix];
        sWd[ix] = w1 - w2; sW2[ix] = w2;
    }
    if (t < H) sb[t] = b[t];
    int i0 = blockIdx.x * 16;
    {
        int row = t >> 4, c4 = t & 15;
        *(float4*)(sh + row * H + c4 * 4) = *(const float4*)(h + (size_t)(i0 + row) * H + c4 * 4);
    }
    __syncthreads();

    int lane = t & 63, w = t >> 6;
    int nl = lane >> 4, cg = lane & 15;
    int node = w * 4 + nl;
    float4 tT = make_float4(0.f, 0.f, 0.f, 0.f);
    float4 tU = make_float4(0.f, 0.f, 0.f, 0.f);
#pragma unroll
    for (int e = 0; e < H; e++) {
        float hv = sh[node * H + e];
        float4 wd = *(const float4*)(sWd + e * H + cg * 4);
        float4 w2 = *(const float4*)(sW2 + e * H + cg * 4);
        tT.x += hv * wd.x; tT.y += hv * wd.y; tT.z += hv * wd.z; tT.w += hv * wd.w;
        tU.x += hv * w2.x; tU.y += hv * w2.y; tU.z += hv * w2.z; tU.w += hv * w2.w;
    }
    float4 bb = *(const float4*)(sb + cg * 4);
    tT.x += bb.x; tT.y += bb.y; tT.z += bb.z; tT.w += bb.w;
    int i = i0 + node;
    *(float4*)(T + (size_t)i * H + cg * 4) = tT;
    *(float4*)(U + (size_t)i * H + cg * 4) = tU;
}

// ---------------------------------------------------------------------------
// Aggregate: h_new[i][c] = h[i][c] + a*ELU(sel_k (T[i][c]+U[j_k][c])) + (be - a*m)
// sel = max if a>=0 else min (ELU monotone). Also writes sq(h_new).
__global__ __launch_bounds__(256) void k_aggr(
    const float* __restrict__ hsrc, const float* __restrict__ T, const float* __restrict__ U,
    const int* __restrict__ knn,
    const float* __restrict__ bn_g, const float* __restrict__ bn_b,
    const float* __restrict__ bn_m, const float* __restrict__ bn_v,
    float* __restrict__ hdst, float* __restrict__ sqdst)
{
    int t = threadIdx.x, w = t >> 6, lane = t & 63;
    int i = blockIdx.x * 4 + w;
    float a = bn_g[lane] * rsqrtf(bn_v[lane] + EPS_BN);
    float cshift = bn_b[lane] - a * bn_m[lane];
    float tv = T[(size_t)i * H + lane];
    int idx[KNN];
#pragma unroll
    for (int k = 0; k < KNN; k++) idx[k] = knn[(size_t)i * KNN + k];
    float mx = -INFF, mn = INFF;
#pragma unroll
    for (int k = 0; k < KNN; k++) {
        float z = tv + U[(size_t)idx[k] * H + lane];
        mx = fmaxf(mx, z); mn = fminf(mn, z);
    }
    float zsel = (a >= 0.f) ? mx : mn;
    float e = zsel > 0.f ? zsel : expm1f(zsel);
    float val = hsrc[(size_t)i * H + lane] + a * e + cshift;
    hdst[(size_t)i * H + lane] = val;
    float s = val * val;
#pragma unroll
    for (int off = 32; off > 0; off >>= 1) s += __shfl_xor(s, off);
    if (lane == 0) sqdst[i] = s;
}

// ---------------------------------------------------------------------------
// Output heads. 16 nodes/block (wave per node, 4 reps). out layout:
// [0,128000): out [16000,8] | [128000,144000): sp | [144000,160000): batch (f32)
__global__ __launch_bounds__(256) void k_heads(
    const float* __restrict__ h,
    const float* __restrict__ oW1, const float* __restrict__ ob1,
    const float* __restrict__ oW2, const float* __restrict__ ob2,
    const float* __restrict__ oW3, const float* __restrict__ ob3,
    const float* __restrict__ pW1, const float* __restrict__ pb1,
    const float* __restrict__ pW2, const float* __restrict__ pb2,
    const float* __restrict__ pW3, const float* __restrict__ pb3,
    float* __restrict__ out)
{
    __shared__ float soW1[H * 64], soW2[64 * 32], soW3[32 * CD];
    __shared__ float spW1s[H * 64], spW2s[64 * 32], spW3s[32];
    __shared__ float sob1[64], sob2[32], sob3[CD], spb1s[64], spb2s[32], spb3s[1];
    __shared__ float sh[4][H];
    __shared__ float sa[4][64], ssp[4][64];
    __shared__ float so2[4][32], ssp2[4][32];

    int t = threadIdx.x, w = t >> 6, lane = t & 63;
    for (int ix = t; ix < H * 64; ix += 256) { soW1[ix] = oW1[ix]; spW1s[ix] = pW1[ix]; }
    for (int ix = t; ix < 64 * 32; ix += 256) { soW2[ix] = oW2[ix]; spW2s[ix] = pW2[ix]; }
    for (int ix = t; ix < 32 * CD; ix += 256) soW3[ix] = oW3[ix];
    if (t < 32) spW3s[t] = pW3[t];
    if (t < 64) { sob1[t] = ob1[t]; spb1s[t] = pb1[t]; }
    if (t < 32) { sob2[t] = ob2[t]; spb2s[t] = pb2[t]; }
    if (t < CD) sob3[t] = ob3[t];
    if (t == 0) spb3s[0] = pb3[0];
    __syncthreads();

    for (int rep = 0; rep < 4; rep++) {
        int i = blockIdx.x * 16 + rep * 4 + w;
        sh[w][lane] = h[(size_t)i * H + lane];
        __syncthreads();
        float a1 = sob1[lane], p1 = spb1s[lane];
#pragma unroll
        for (int k = 0; k < H; k++) {
            float hv = sh[w][k];
            a1 += hv * soW1[k * 64 + lane];
            p1 += hv * spW1s[k * 64 + lane];
        }
        a1 = a1 > 0.f ? a1 : expm1f(a1);
        p1 = p1 > 0.f ? p1 : expm1f(p1);
        sa[w][lane] = a1; ssp[w][lane] = p1;
        __syncthreads();
        if (lane < 32) {
            float o2 = sob2[lane], q2 = spb2s[lane];
#pragma unroll
            for (int k = 0; k < 64; k++) {
                o2 += sa[w][k] * soW2[k * 32 + lane];
                q2 += ssp[w][k] * spW2s[k * 32 + lane];
            }
            o2 = o2 > 0.f ? o2 : expm1f(o2);
            q2 = q2 > 0.f ? q2 : expm1f(q2);
            so2[w][lane] = o2; ssp2[w][lane] = q2;
        }
        __syncthreads();
        if (lane < CD) {
            float o3 = sob3[lane];
#pragma unroll
            for (int k = 0; k < 32; k++) o3 += so2[w][k] * soW3[k * CD + lane];
            out[(size_t)i * CD + lane] = o3;
        }
        if (lane == 32) {
            float s3 = spb3s[0];
#pragma unroll
            for (int k = 0; k < 32; k++) s3 += ssp2[w][k] * spW3s[k];
            out[(size_t)N_NODES * CD + i] = s3;
        }
        if (lane == 33) out[(size_t)N_NODES * CD + N_NODES + i] = (float)(i / NPG);
        __syncthreads();
    }
}

// ---------------------------------------------------------------------------
extern "C" void kernel_launch(void* const* d_in, const int* in_sizes, int n_in,
                              void* d_out, int out_size, void* d_ws, size_t ws_size,
                              hipStream_t stream)
{
    const float* x     = (const float*)d_in[0];
    // d_in[1] = batch (values reproduced analytically)
    const float* lcW1  = (const float*)d_in[2];  const float* lcb1 = (const float*)d_in[3];
    const float* lcW2  = (const float*)d_in[4];  const float* lcb2 = (const float*)d_in[5];
    const float* convW = (const float*)d_in[6];  const float* convb = (const float*)d_in[7];
    const float* bn_g  = (const float*)d_in[8];  const float* bn_b = (const float*)d_in[9];
    const float* bn_m  = (const float*)d_in[10]; const float* bn_v = (const float*)d_in[11];
    const float* outW1 = (const float*)d_in[12]; const float* outb1 = (const float*)d_in[13];
    const float* outW2 = (const float*)d_in[14]; const float* outb2 = (const float*)d_in[15];
    const float* outW3 = (const float*)d_in[16]; const float* outb3 = (const float*)d_in[17];
    const float* spW1  = (const float*)d_in[18]; const float* spb1 = (const float*)d_in[19];
    const float* spW2  = (const float*)d_in[20]; const float* spb2 = (const float*)d_in[21];
    const float* spW3  = (const float*)d_in[22]; const float* spb3 = (const float*)d_in[23];

    float* ws  = (float*)d_ws;
    float* hA  = ws;                       // 1,024,000 floats
    float* hB  = hA + (size_t)N_NODES * H;
    float* sqA = hB + (size_t)N_NODES * H;
    float* sqB = sqA + N_NODES;
    float* T   = sqB + N_NODES;
    float* U   = T + (size_t)N_NODES * H;
    int*   knn = (int*)(U + (size_t)N_NODES * H);

    k_lc_encode<<<N_NODES / 4, 256, 0, stream>>>(x, lcW1, lcb1, lcW2, lcb2, hA, sqA);

    float* src = hA; float* ssq = sqA; float* dst = hB; float* dsq = sqB;
    for (int l = 0; l < NLAYERS; l++) {
        k_knn<<<NGRAPH * IBLK, 256, 0, stream>>>(src, ssq, knn);
        k_tu<<<N_NODES / 16, 256, 0, stream>>>(src, convW + (size_t)l * 2 * H * H,
                                               convb + (size_t)l * H, T, U);
        k_aggr<<<N_NODES / 4, 256, 0, stream>>>(src, T, U, knn,
                                                bn_g + (size_t)l * H, bn_b + (size_t)l * H,
                                                bn_m + (size_t)l * H, bn_v + (size_t)l * H,
                                                dst, dsq);
        float* tmp = src; src = dst; dst = tmp;
        tmp = ssq; ssq = dsq; dsq = tmp;
    }

    k_heads<<<N_NODES / 16, 256, 0, stream>>>(src,
        outW1, outb1, outW2, outb2, outW3, outb3,
        spW1, spb1, spW2, spb2, spW3, spb3, (float*)d_out);
}

// Round 2
// 801.545 us; speedup vs baseline: 15.9020x; 15.9020x over previous
//
#include <hip/hip_runtime.h>
#include <math.h>

#define N_NODES 16000
#define NGRAPH  16
#define NPG     1000      // nodes per graph
#define H       64
#define KNN     20
#define DIN     8
#define HID     32
#define NLAYERS 4
#define CD      8
#define EPS_BN  1e-5f
#define TI      16        // i-nodes per kNN block
#define IBLK    63        // ceil(1000/16)
#define INFF    __builtin_inff()

// ---------------------------------------------------------------------------
// lc_encode: x[16000,8] -> Linear(8,32)+ELU -> Linear(32,64)+ELU -> h ; also sq
// wave per node, 4 nodes/block
__global__ __launch_bounds__(256) void k_lc_encode(
    const float* __restrict__ x, const float* __restrict__ W1, const float* __restrict__ b1,
    const float* __restrict__ W2, const float* __restrict__ b2,
    float* __restrict__ h, float* __restrict__ sq)
{
    __shared__ float sW1[DIN * HID];
    __shared__ float sb1[HID];
    __shared__ float sW2[HID * H];
    __shared__ float sb2[H];
    __shared__ float sx[4][DIN];
    __shared__ float sa1[4][HID];

    int t = threadIdx.x;
    for (int ix = t; ix < DIN * HID; ix += 256) sW1[ix] = W1[ix];
    for (int ix = t; ix < HID * H;  ix += 256) sW2[ix] = W2[ix];
    if (t < HID) sb1[t] = b1[t];
    if (t < H)   sb2[t] = b2[t];

    int w = t >> 6, lane = t & 63;
    int i = blockIdx.x * 4 + w;
    if (lane < DIN) sx[w][lane] = x[i * DIN + lane];
    __syncthreads();

    // stage 1 (32 outputs; lanes 32..63 duplicate to keep flow uniform)
    int c = lane & 31;
    float a1 = sb1[c];
#pragma unroll
    for (int k = 0; k < DIN; k++) a1 += sx[w][k] * sW1[k * HID + c];
    a1 = a1 > 0.f ? a1 : expm1f(a1);
    if (lane < HID) sa1[w][lane] = a1;
    __syncthreads();

    // stage 2 (64 outputs)
    float acc = sb2[lane];
#pragma unroll
    for (int k = 0; k < HID; k++) acc += sa1[w][k] * sW2[k * H + lane];
    acc = acc > 0.f ? acc : expm1f(acc);
    h[i * H + lane] = acc;

    float s = acc * acc;
#pragma unroll
    for (int off = 32; off > 0; off >>= 1) s += __shfl_xor(s, off);
    if (lane == 0) sq[i] = s;
}

// ---------------------------------------------------------------------------
// Fused kNN: per block 16 i-nodes of one graph. d2(i,j) = sq_i + sq_j - 2*dot.
// Each wave owns 4 i's; lane covers j = lane + 64*r (r=0..15) with d2 in regs.
// Two j-tiles staged per barrier (shj[2]) so the broadcast reads of the i-rows
// are amortized across 2 tiles. NO min-occupancy bound: d2r[4][16] must stay
// in VGPRs (round 1's __launch_bounds__(256,4) spilled it -> 10 GB scratch).
__global__ __launch_bounds__(256, 2) void k_knn(
    const float* __restrict__ h, const float* __restrict__ sq, int* __restrict__ knn)
{
    __shared__ float shi[TI * H];        // 16 rows x 64 (broadcast reads -> no pad)
    __shared__ float ssqi[TI];
    __shared__ float shj[2][64 * 64];    // 2 tiles x 64 rows x 16 float4, xor-swizzled
    __shared__ float ssqj[2][64];

    int g  = blockIdx.x / IBLK;
    int ib = blockIdx.x % IBLK;
    int i0 = ib * TI;                    // graph-local
    int t = threadIdx.x, w = t >> 6, lane = t & 63;
    const float* hg  = h  + (size_t)g * NPG * H;
    const float* sqg = sq + (size_t)g * NPG;

    // stage hi tile: 16x64 floats = 256 float4, one per thread
    {
        int row = t >> 4, c4 = t & 15;
        int i = i0 + row;
        float4 v = make_float4(0.f, 0.f, 0.f, 0.f);
        if (i < NPG) v = *(const float4*)(hg + i * H + c4 * 4);
        *(float4*)(shi + row * H + c4 * 4) = v;
        if (t < TI) ssqi[t] = (i0 + t < NPG) ? sqg[i0 + t] : 0.f;
    }
    __syncthreads();

    float sqi[4];
#pragma unroll
    for (int ii = 0; ii < 4; ii++) sqi[ii] = ssqi[w * 4 + ii];

    float d2r[4][16];

#pragma unroll 1
    for (int rg = 0; rg < 8; rg++) {
        if (rg) __syncthreads();         // previous tile-pair's compute done
        // stage 2 j-tiles (128 nodes x 64 floats), xor-swizzled at float4 level
#pragma unroll
        for (int p = 0; p < 8; p++) {
            int f = t + 256 * p;         // 0..2047
            int tile = f >> 10;
            int fi = f & 1023;
            int row = fi >> 4, c4 = fi & 15;
            int jl = rg * 128 + tile * 64 + row;
            float4 v = make_float4(0.f, 0.f, 0.f, 0.f);
            if (jl < NPG) v = *(const float4*)(hg + jl * H + c4 * 4);
            *(float4*)(&shj[tile][(row * 16 + (c4 ^ (row & 15))) * 4]) = v;
        }
        if (t < 128) {
            int jl = rg * 128 + t;
            ssqj[t >> 6][t & 63] = (jl < NPG) ? sqg[jl] : 0.f;
        }
        __syncthreads();

        float sqj0 = ssqj[0][lane];
        float sqj1 = ssqj[1][lane];
        float a00 = 0.f, a10 = 0.f, a20 = 0.f, a30 = 0.f;   // tile 0
        float a01 = 0.f, a11 = 0.f, a21 = 0.f, a31 = 0.f;   // tile 1
#pragma unroll
        for (int kc = 0; kc < 16; kc++) {
            int bo = (lane * 16 + (kc ^ (lane & 15))) * 4;
            float4 b0 = *(const float4*)(&shj[0][bo]);
            float4 b1 = *(const float4*)(&shj[1][bo]);
            float4 r0 = *(const float4*)(shi + (w * 4 + 0) * H + kc * 4);
            float4 r1 = *(const float4*)(shi + (w * 4 + 1) * H + kc * 4);
            float4 r2 = *(const float4*)(shi + (w * 4 + 2) * H + kc * 4);
            float4 r3 = *(const float4*)(shi + (w * 4 + 3) * H + kc * 4);
            a00 += r0.x * b0.x + r0.y * b0.y + r0.z * b0.z + r0.w * b0.w;
            a10 += r1.x * b0.x + r1.y * b0.y + r1.z * b0.z + r1.w * b0.w;
            a20 += r2.x * b0.x + r2.y * b0.y + r2.z * b0.z + r2.w * b0.w;
            a30 += r3.x * b0.x + r3.y * b0.y + r3.z * b0.z + r3.w * b0.w;
            a01 += r0.x * b1.x + r0.y * b1.y + r0.z * b1.z + r0.w * b1.w;
            a11 += r1.x * b1.x + r1.y * b1.y + r1.z * b1.z + r1.w * b1.w;
            a21 += r2.x * b1.x + r2.y * b1.y + r2.z * b1.z + r2.w * b1.w;
            a31 += r3.x * b1.x + r3.y * b1.y + r3.z * b1.z + r3.w * b1.w;
        }
        int j0 = rg * 128 + lane;
        int j1 = j0 + 64;
        bool ok0 = (j0 < NPG), ok1 = (j1 < NPG);
        d2r[0][rg * 2 + 0] = ok0 ? (sqi[0] + sqj0 - 2.f * a00) : INFF;
        d2r[1][rg * 2 + 0] = ok0 ? (sqi[1] + sqj0 - 2.f * a10) : INFF;
        d2r[2][rg * 2 + 0] = ok0 ? (sqi[2] + sqj0 - 2.f * a20) : INFF;
        d2r[3][rg * 2 + 0] = ok0 ? (sqi[3] + sqj0 - 2.f * a30) : INFF;
        d2r[0][rg * 2 + 1] = ok1 ? (sqi[0] + sqj1 - 2.f * a01) : INFF;
        d2r[1][rg * 2 + 1] = ok1 ? (sqi[1] + sqj1 - 2.f * a11) : INFF;
        d2r[2][rg * 2 + 1] = ok1 ? (sqi[2] + sqj1 - 2.f * a21) : INFF;
        d2r[3][rg * 2 + 1] = ok1 ? (sqi[3] + sqj1 - 2.f * a31) : INFF;
    }

    // top-KNN selection, registers + shuffles only.  j = r*64 + lane.
#pragma unroll 1
    for (int ii = 0; ii < 4; ii++) {
        int i_loc = i0 + w * 4 + ii;
        float bv = INFF; int br = 0;
#pragma unroll
        for (int r = 0; r < 16; r++) { float v = d2r[ii][r]; if (v < bv) { bv = v; br = r; } }
        int bj = br * 64 + lane;
        int myj = 0;
#pragma unroll 1
        for (int round = 0; round < KNN; round++) {
            float v = bv; int jj = bj;
#pragma unroll
            for (int off = 1; off < 64; off <<= 1) {
                float ov = __shfl_xor(v, off);
                int   oj = __shfl_xor(jj, off);
                if (ov < v || (ov == v && oj < jj)) { v = ov; jj = oj; }
            }
            if (lane == round) myj = jj;     // lanes 0..19 collect winners in order
            if ((jj & 63) == lane) {         // owner invalidates + rescans
                int wr = jj >> 6;
                bv = INFF; br = 0;
#pragma unroll
                for (int r = 0; r < 16; r++) {
                    if (r == wr) d2r[ii][r] = INFF;
                    float vv = d2r[ii][r];
                    if (vv < bv) { bv = vv; br = r; }
                }
                bj = br * 64 + lane;
            }
        }
        if (lane < KNN && i_loc < NPG)
            knn[(size_t)(g * NPG + i_loc) * KNN + lane] = g * NPG + myj;
    }
}

// ---------------------------------------------------------------------------
// T = h @ (W1 - W2) + b ; U = h @ W2.   W: [128][64] (rows 0..63 = x_i part).
__global__ __launch_bounds__(256) void k_tu(
    const float* __restrict__ h, const float* __restrict__ W, const float* __restrict__ b,
    float* __restrict__ T, float* __restrict__ U)
{
    __shared__ float sWd[H * H];
    __shared__ float sW2[H * H];
    __shared__ float sh[16 * H];
    __shared__ float sb[H];
    int t = threadIdx.x;
    for (int ix = t; ix < H * H; ix += 256) {
        float w1 = W[ix], w2 = W[H * H + ix];
        sWd[ix] = w1 - w2; sW2[ix] = w2;
    }
    if (t < H) sb[t] = b[t];
    int i0 = blockIdx.x * 16;
    {
        int row = t >> 4, c4 = t & 15;
        *(float4*)(sh + row * H + c4 * 4) = *(const float4*)(h + (size_t)(i0 + row) * H + c4 * 4);
    }
    __syncthreads();

    int lane = t & 63, w = t >> 6;
    int nl = lane >> 4, cg = lane & 15;
    int node = w * 4 + nl;
    float4 tT = make_float4(0.f, 0.f, 0.f, 0.f);
    float4 tU = make_float4(0.f, 0.f, 0.f, 0.f);
#pragma unroll
    for (int e = 0; e < H; e++) {
        float hv = sh[node * H + e];
        float4 wd = *(const float4*)(sWd + e * H + cg * 4);
        float4 w2 = *(const float4*)(sW2 + e * H + cg * 4);
        tT.x += hv * wd.x; tT.y += hv * wd.y; tT.z += hv * wd.z; tT.w += hv * wd.w;
        tU.x += hv * w2.x; tU.y += hv * w2.y; tU.z += hv * w2.z; tU.w += hv * w2.w;
    }
    float4 bb = *(const float4*)(sb + cg * 4);
    tT.x += bb.x; tT.y += bb.y; tT.z += bb.z; tT.w += bb.w;
    int i = i0 + node;
    *(float4*)(T + (size_t)i * H + cg * 4) = tT;
    *(float4*)(U + (size_t)i * H + cg * 4) = tU;
}

// ---------------------------------------------------------------------------
// Aggregate: h_new[i][c] = h[i][c] + a*ELU(sel_k (T[i][c]+U[j_k][c])) + (be - a*m)
// sel = max if a>=0 else min (ELU monotone). Also writes sq(h_new).
__global__ __launch_bounds__(256) void k_aggr(
    const float* __restrict__ hsrc, const float* __restrict__ T, const float* __restrict__ U,
    const int* __restrict__ knn,
    const float* __restrict__ bn_g, const float* __restrict__ bn_b,
    const float* __restrict__ bn_m, const float* __restrict__ bn_v,
    float* __restrict__ hdst, float* __restrict__ sqdst)
{
    int t = threadIdx.x, w = t >> 6, lane = t & 63;
    int i = blockIdx.x * 4 + w;
    float a = bn_g[lane] * rsqrtf(bn_v[lane] + EPS_BN);
    float cshift = bn_b[lane] - a * bn_m[lane];
    float tv = T[(size_t)i * H + lane];
    int idx[KNN];
#pragma unroll
    for (int k = 0; k < KNN; k++) idx[k] = knn[(size_t)i * KNN + k];
    float mx = -INFF, mn = INFF;
#pragma unroll
    for (int k = 0; k < KNN; k++) {
        float z = tv + U[(size_t)idx[k] * H + lane];
        mx = fmaxf(mx, z); mn = fminf(mn, z);
    }
    float zsel = (a >= 0.f) ? mx : mn;
    float e = zsel > 0.f ? zsel : expm1f(zsel);
    float val = hsrc[(size_t)i * H + lane] + a * e + cshift;
    hdst[(size_t)i * H + lane] = val;
    float s = val * val;
#pragma unroll
    for (int off = 32; off > 0; off >>= 1) s += __shfl_xor(s, off);
    if (lane == 0) sqdst[i] = s;
}

// ---------------------------------------------------------------------------
// Output heads. 16 nodes/block (wave per node, 4 reps). out layout:
// [0,128000): out [16000,8] | [128000,144000): sp | [144000,160000): batch (f32)
__global__ __launch_bounds__(256) void k_heads(
    const float* __restrict__ h,
    const float* __restrict__ oW1, const float* __restrict__ ob1,
    const float* __restrict__ oW2, const float* __restrict__ ob2,
    const float* __restrict__ oW3, const float* __restrict__ ob3,
    const float* __restrict__ pW1, const float* __restrict__ pb1,
    const float* __restrict__ pW2, const float* __restrict__ pb2,
    const float* __restrict__ pW3, const float* __restrict__ pb3,
    float* __restrict__ out)
{
    __shared__ float soW1[H * 64], soW2[64 * 32], soW3[32 * CD];
    __shared__ float spW1s[H * 64], spW2s[64 * 32], spW3s[32];
    __shared__ float sob1[64], sob2[32], sob3[CD], spb1s[64], spb2s[32], spb3s[1];
    __shared__ float sh[4][H];
    __shared__ float sa[4][64], ssp[4][64];
    __shared__ float so2[4][32], ssp2[4][32];

    int t = threadIdx.x, w = t >> 6, lane = t & 63;
    for (int ix = t; ix < H * 64; ix += 256) { soW1[ix] = oW1[ix]; spW1s[ix] = pW1[ix]; }
    for (int ix = t; ix < 64 * 32; ix += 256) { soW2[ix] = oW2[ix]; spW2s[ix] = pW2[ix]; }
    for (int ix = t; ix < 32 * CD; ix += 256) soW3[ix] = oW3[ix];
    if (t < 32) spW3s[t] = pW3[t];
    if (t < 64) { sob1[t] = ob1[t]; spb1s[t] = pb1[t]; }
    if (t < 32) { sob2[t] = ob2[t]; spb2s[t] = pb2[t]; }
    if (t < CD) sob3[t] = ob3[t];
    if (t == 0) spb3s[0] = pb3[0];
    __syncthreads();

    for (int rep = 0; rep < 4; rep++) {
        int i = blockIdx.x * 16 + rep * 4 + w;
        sh[w][lane] = h[(size_t)i * H + lane];
        __syncthreads();
        float a1 = sob1[lane], p1 = spb1s[lane];
#pragma unroll
        for (int k = 0; k < H; k++) {
            float hv = sh[w][k];
            a1 += hv * soW1[k * 64 + lane];
            p1 += hv * spW1s[k * 64 + lane];
        }
        a1 = a1 > 0.f ? a1 : expm1f(a1);
        p1 = p1 > 0.f ? p1 : expm1f(p1);
        sa[w][lane] = a1; ssp[w][lane] = p1;
        __syncthreads();
        if (lane < 32) {
            float o2 = sob2[lane], q2 = spb2s[lane];
#pragma unroll
            for (int k = 0; k < 64; k++) {
                o2 += sa[w][k] * soW2[k * 32 + lane];
                q2 += ssp[w][k] * spW2s[k * 32 + lane];
            }
            o2 = o2 > 0.f ? o2 : expm1f(o2);
            q2 = q2 > 0.f ? q2 : expm1f(q2);
            so2[w][lane] = o2; ssp2[w][lane] = q2;
        }
        __syncthreads();
        if (lane < CD) {
            float o3 = sob3[lane];
#pragma unroll
            for (int k = 0; k < 32; k++) o3 += so2[w][k] * soW3[k * CD + lane];
            out[(size_t)i * CD + lane] = o3;
        }
        if (lane == 32) {
            float s3 = spb3s[0];
#pragma unroll
            for (int k = 0; k < 32; k++) s3 += ssp2[w][k] * spW3s[k];
            out[(size_t)N_NODES * CD + i] = s3;
        }
        if (lane == 33) out[(size_t)N_NODES * CD + N_NODES + i] = (float)(i / NPG);
        __syncthreads();
    }
}

// ---------------------------------------------------------------------------
extern "C" void kernel_launch(void* const* d_in, const int* in_sizes, int n_in,
                              void* d_out, int out_size, void* d_ws, size_t ws_size,
                              hipStream_t stream)
{
    const float* x     = (const float*)d_in[0];
    // d_in[1] = batch (values reproduced analytically)
    const float* lcW1  = (const float*)d_in[2];  const float* lcb1 = (const float*)d_in[3];
    const float* lcW2  = (const float*)d_in[4];  const float* lcb2 = (const float*)d_in[5];
    const float* convW = (const float*)d_in[6];  const float* convb = (const float*)d_in[7];
    const float* bn_g  = (const float*)d_in[8];  const float* bn_b = (const float*)d_in[9];
    const float* bn_m  = (const float*)d_in[10]; const float* bn_v = (const float*)d_in[11];
    const float* outW1 = (const float*)d_in[12]; const float* outb1 = (const float*)d_in[13];
    const float* outW2 = (const float*)d_in[14]; const float* outb2 = (const float*)d_in[15];
    const float* outW3 = (const float*)d_in[16]; const float* outb3 = (const float*)d_in[17];
    const float* spW1  = (const float*)d_in[18]; const float* spb1 = (const float*)d_in[19];
    const float* spW2  = (const float*)d_in[20]; const float* spb2 = (const float*)d_in[21];
    const float* spW3  = (const float*)d_in[22]; const float* spb3 = (const float*)d_in[23];

    float* ws  = (float*)d_ws;
    float* hA  = ws;                       // 1,024,000 floats
    float* hB  = hA + (size_t)N_NODES * H;
    float* sqA = hB + (size_t)N_NODES * H;
    float* sqB = sqA + N_NODES;
    float* T   = sqB + N_NODES;
    float* U   = T + (size_t)N_NODES * H;
    int*   knn = (int*)(U + (size_t)N_NODES * H);

    k_lc_encode<<<N_NODES / 4, 256, 0, stream>>>(x, lcW1, lcb1, lcW2, lcb2, hA, sqA);

    float* src = hA; float* ssq = sqA; float* dst = hB; float* dsq = sqB;
    for (int l = 0; l < NLAYERS; l++) {
        k_knn<<<NGRAPH * IBLK, 256, 0, stream>>>(src, ssq, knn);
        k_tu<<<N_NODES / 16, 256, 0, stream>>>(src, convW + (size_t)l * 2 * H * H,
                                               convb + (size_t)l * H, T, U);
        k_aggr<<<N_NODES / 4, 256, 0, stream>>>(src, T, U, knn,
                                                bn_g + (size_t)l * H, bn_b + (size_t)l * H,
                                                bn_m + (size_t)l * H, bn_v + (size_t)l * H,
                                                dst, dsq);
        float* tmp = src; src = dst; dst = tmp;
        tmp = ssq; ssq = dsq; dsq = tmp;
    }

    k_heads<<<N_NODES / 16, 256, 0, stream>>>(src,
        outW1, outb1, outW2, outb2, outW3, outb3,
        spW1, spb1, spW2, spb2, spW3, spb3, (float*)d_out);
}